// Round 4
// baseline (555.777 us; speedup 1.0000x reference)
//
#include <hip/hip_runtime.h>

// expRNN/modReLU recurrence, B=8192, T=784, I=1, H=30, C=10.
//
// Round 9: MFMA rewrite. R6-R8 showed the fp32-VALU dataflow is issue-floor
// limited (~400 cyc/step/8 batches; measured 575-650) and immune to source
// scheduling. MfmaUtil was 0.0 all along. New structure:
//   - one wave = 32 batches; step is Z^T[32x32] = W_hh[32x32] . H^T[32x32]
//     via v_mfma_f32_32x32x16_bf16, K split in 2 chunks (k0-15, k16-31).
//   - precision: W 3-split (w1+w2+w3, bf16 each), H 3-split (h1+h2+h3);
//     products kept: w1h1,w1h2,w2h1,w1h3,w2h2,w3h1 per chunk = 12 MFMA/step.
//     Effective map error ~2^-24: indistinguishable from fp32 reorder noise.
//   - D-layout (verified m74/m101): col=lane&31=batch, row=(reg&3)+8(reg>>2)
//     +4*(lane>>5). Next step's B-frag (k=8*sg+e per chunk) = in-lane packed
//     pairs + 4 v_permlane32_swap_b32 per split level. No LDS in the chain.
//   - modReLU + x-term in fp32 on the 16 acc elements; C-init = wih[r]*x.
//   - x staged in LDS (b-major, XPAD=788), 1 ds_read_b32/step (4-way bank
//     conflict = ~+3cyc, acceptable); gfx950 static LDS 105KB OK (<160K).
// Predict: ~500 cyc/step issue-bound -> dispatch 165-200us, MfmaUtil 15-25%,
// VALUBusy 70-80%, VGPR ~190, 1 wave/CU.

#define T_STEPS 784
#define NBATCH  8192
#define NH      30
#define NC      10
#define BPW     32            // batches per wave/block
#define XPAD    788           // x row pad: %4==0 for float4 preload

typedef float  f32x16 __attribute__((ext_vector_type(16)));
typedef short  s16x8  __attribute__((ext_vector_type(8)));
typedef int    i32x4  __attribute__((ext_vector_type(4)));

#define MFMA32(a, b, c) __builtin_amdgcn_mfma_f32_32x32x16_bf16(a, b, c, 0, 0, 0)

// packed bf16 pair: lo16 = bf16(lo), hi16 = bf16(hi), RNE
__device__ __forceinline__ int cvt_pk_bf16(float lo, float hi) {
    int d;
    asm("v_cvt_pk_bf16_f32 %0, %1, %2" : "=v"(d) : "v"(lo), "v"(hi));
    return d;
}

// v_permlane32_swap_b32: x.hi32lanes <-> y.lo32lanes.
// After: x = lanes<32: own x | lanes>=32: y from lane-32
//        y = lanes<32: x from lane+32 | lanes>=32: own y
__device__ __forceinline__ void permswap(int &x, int &y) {
#if __has_builtin(__builtin_amdgcn_permlane32_swap)
    auto rr = __builtin_amdgcn_permlane32_swap(x, y, false, false);
    int t0, t1;
    __builtin_memcpy(&t0, (const char*)&rr, 4);
    __builtin_memcpy(&t1, (const char*)&rr + 4, 4);
    x = t0; y = t1;
#else
    asm volatile("s_nop 1\n\tv_permlane32_swap_b32 %0, %1\n\ts_nop 1"
                 : "+v"(x), "+v"(y));
#endif
}

__device__ __forceinline__ float rne_bf16(float x) {
    unsigned u = __float_as_uint(x);
    u = (u + 0x7fffu + ((u >> 16) & 1u)) & 0xffff0000u;
    return __uint_as_float(u);
}

__device__ __forceinline__ s16x8 pack8(const float* v) {
    i32x4 t;
    t.x = cvt_pk_bf16(v[0], v[1]);
    t.y = cvt_pk_bf16(v[2], v[3]);
    t.z = cvt_pk_bf16(v[4], v[5]);
    t.w = cvt_pk_bf16(v[6], v[7]);
    return __builtin_bit_cast(s16x8, t);
}

__global__ __launch_bounds__(64, 1)
void rnn_mfma(const float* __restrict__ inp,    // [B, T, 1]
              const float* __restrict__ W_ih,   // [H, 1]
              const float* __restrict__ W_hh,   // [H, H]
              const float* __restrict__ b_mod,  // [H]
              const float* __restrict__ W_lin,  // [C, H]
              const float* __restrict__ b_lin,  // [C]
              float* __restrict__ out)          // [B, C]
{
    __shared__ __align__(16) float xl[BPW * XPAD];   // 100.9 KB
    __shared__ float hfin[BPW * 33];                  // 4.2 KB, pad 33

    const int l   = threadIdx.x;
    const int blk = blockIdx.x;
    const int b   = l & 31;      // batch column (j) owned by this lane
    const int sg  = l >> 5;      // half-wave index

    // ---- preload x: 32 batches x 784 floats, coalesced float4 ----
    {
        const float4* src = (const float4*)(inp + (size_t)blk * (BPW * T_STEPS));
        #pragma unroll 1
        for (int k = 0; k < 98; ++k) {               // 98*64 = 6272 float4 exact
            int v   = l + 64 * k;
            int bb  = v / 196;                        // 196 float4 per batch row
            int rem = v - bb * 196;
            *(float4*)(xl + bb * XPAD + 4 * rem) = src[v];
        }
    }
    __syncthreads();

    // ---- W_hh A-fragments: 3 split levels x 2 K-chunks ----
    // A[i][k]: i = lane&31 (assumed), k = chunk*16 + 8*sg + e, e=0..7
    s16x8 wA[3][2];
    {
        #pragma unroll
        for (int c = 0; c < 2; ++c) {
            float w1f[8], w2f[8], w3f[8];
            #pragma unroll
            for (int e = 0; e < 8; ++e) {
                int k = 16 * c + 8 * sg + e;
                float w  = (b < NH && k < NH) ? W_hh[b * NH + k] : 0.0f;
                float a1 = rne_bf16(w);  float r1 = w  - a1;
                float a2 = rne_bf16(r1); float r2 = r1 - a2;
                float a3 = rne_bf16(r2);
                w1f[e] = a1; w2f[e] = a2; w3f[e] = a3;
            }
            wA[0][c] = pack8(w1f);
            wA[1][c] = pack8(w2f);
            wA[2][c] = pack8(w3f);
        }
    }

    // ---- per-acc-reg constants: r(j) = (j&3) + 8*(j>>2) + 4*sg ----
    float wihr[16], bmr[16];
    #pragma unroll
    for (int j = 0; j < 16; ++j) {
        int r = (j & 3) + 8 * (j >> 2) + 4 * sg;
        wihr[j] = (r < NH) ? W_ih[r]  : 0.0f;
        bmr[j]  = (r < NH) ? b_mod[r] : 0.0f;
    }

    f32x16 czero;
    #pragma unroll
    for (int j = 0; j < 16; ++j) czero[j] = 0.0f;

    // ---- state: B-fragments (h split levels), start at h=0 ----
    s16x8 fB[3][2];
    {
        i32x4 zi = {0, 0, 0, 0};
        s16x8 z8 = __builtin_bit_cast(s16x8, zi);
        #pragma unroll
        for (int lv = 0; lv < 3; ++lv) { fB[lv][0] = z8; fB[lv][1] = z8; }
    }

    float hq[16];                 // final h (fp32) for classifier
    const float* xb = xl + b * XPAD;
    float xcur = xb[0];

    #pragma unroll 1
    for (int t = 0; t < T_STEPS; ++t) {
        float xnext = xb[t + 1];             // t=783 reads pad slot 784 < 788

        // C-init: x-term (wih[r] * x_b), chunk0 acc; chunk1 acc starts 0
        f32x16 cA;
        #pragma unroll
        for (int j = 0; j < 16; ++j) cA[j] = wihr[j] * xcur;

        // 6 products per chunk, two interleaved acc chains
        f32x16 accA, accB;
        accA = MFMA32(wA[0][0], fB[0][0], cA);     // w1 h1  (k 0-15)
        accB = MFMA32(wA[0][1], fB[0][1], czero);  // w1 h1  (k 16-31)
        accA = MFMA32(wA[0][0], fB[1][0], accA);   // w1 h2
        accB = MFMA32(wA[0][1], fB[1][1], accB);
        accA = MFMA32(wA[1][0], fB[0][0], accA);   // w2 h1
        accB = MFMA32(wA[1][1], fB[0][1], accB);
        accA = MFMA32(wA[0][0], fB[2][0], accA);   // w1 h3
        accB = MFMA32(wA[0][1], fB[2][1], accB);
        accA = MFMA32(wA[1][0], fB[1][0], accA);   // w2 h2
        accB = MFMA32(wA[1][1], fB[1][1], accB);
        accA = MFMA32(wA[2][0], fB[0][0], accA);   // w3 h1
        accB = MFMA32(wA[2][1], fB[0][1], accB);

        // z = accA + accB; modReLU
        #pragma unroll
        for (int j = 0; j < 16; ++j) {
            float z = accA[j] + accB[j];
            float m = fmaxf(fabsf(z) + bmr[j], 0.0f);
            hq[j] = copysignf(m, z);
        }

        // split h into 3 bf16 levels, packed in r-pairs:
        // P[q] = pk(h[2q], h[2q+1]) covers r-pair base: q=0:4sg, 1:4sg+2,
        // 2:8+4sg, 3:8+4sg+2, 4:16+4sg, 5:16+4sg+2, 6:24+4sg, 7:24+4sg+2
        int P1[8], P2[8], P3[8];
        #pragma unroll
        for (int q = 0; q < 8; ++q) {
            float a = hq[2 * q], c = hq[2 * q + 1];
            int p1 = cvt_pk_bf16(a, c);
            float ua = __uint_as_float(((unsigned)p1) << 16);
            float uc = __uint_as_float(((unsigned)p1) & 0xffff0000u);
            float ra = a - ua, rc = c - uc;
            int p2 = cvt_pk_bf16(ra, rc);
            float va = __uint_as_float(((unsigned)p2) << 16);
            float vc = __uint_as_float(((unsigned)p2) & 0xffff0000u);
            int p3 = cvt_pk_bf16(ra - va, rc - vc);
            P1[q] = p1; P2[q] = p2; P3[q] = p3;
        }

        // redistribute to B-frags: chunk0 = {P0,P1,P2,P3} after swaps,
        // chunk1 = {P4,P5,P6,P7} after swaps (cross-half via permlane32_swap)
#define SWAPBUILD(P, lv) { \
        int a0 = P[0], a1 = P[1], a2 = P[2], a3 = P[3]; \
        int a4 = P[4], a5 = P[5], a6 = P[6], a7 = P[7]; \
        permswap(a0, a2); permswap(a1, a3); \
        permswap(a4, a6); permswap(a5, a7); \
        i32x4 t0 = {a0, a1, a2, a3}; \
        i32x4 t1 = {a4, a5, a6, a7}; \
        fB[lv][0] = __builtin_bit_cast(s16x8, t0); \
        fB[lv][1] = __builtin_bit_cast(s16x8, t1); \
}
        SWAPBUILD(P1, 0)
        SWAPBUILD(P2, 1)
        SWAPBUILD(P3, 2)
#undef SWAPBUILD

        xcur = xnext;
    }

    // ---- stash h for classifier: hfin[b][r], stride 33 (conflict-free) ----
    #pragma unroll
    for (int j = 0; j < 16; ++j) {
        int r = (j & 3) + 8 * (j >> 2) + 4 * sg;
        hfin[b * 33 + r] = hq[j];            // r=30,31 pad writes harmless
    }
    __syncthreads();

    // ---- classifier: 320 outputs (32 batches x 10 classes), 5 per lane ----
    #pragma unroll
    for (int it = 0; it < 5; ++it) {
        int kk = l + 64 * it;                // < 320 always (64*5 = 320)
        int bb = kk / 10;
        int c  = kk - bb * 10;
        float acc = b_lin[c];
        #pragma unroll
        for (int i = 0; i < NH; ++i) {
            acc = fmaf(W_lin[c * NH + i], hfin[bb * 33 + i], acc);
        }
        out[((size_t)blk * BPW + bb) * NC + c] = acc;
    }
}

extern "C" void kernel_launch(void* const* d_in, const int* in_sizes, int n_in,
                              void* d_out, int out_size, void* d_ws, size_t ws_size,
                              hipStream_t stream) {
    const float* inp   = (const float*)d_in[0];
    const float* W_ih  = (const float*)d_in[1];
    const float* W_hh  = (const float*)d_in[2];
    const float* b_mod = (const float*)d_in[3];
    const float* W_lin = (const float*)d_in[4];
    const float* b_lin = (const float*)d_in[5];
    float* out = (float*)d_out;

    dim3 grid(NBATCH / BPW);   // 256 blocks, one wave each (1/CU)
    dim3 block(64);
    rnn_mfma<<<grid, block, 0, stream>>>(inp, W_ih, W_hh, b_mod,
                                         W_lin, b_lin, out);
}

// Round 5
// 519.582 us; speedup vs baseline: 1.0697x; 1.0697x over previous
//
#include <hip/hip_runtime.h>

// expRNN/modReLU recurrence, B=8192, T=784, I=1, H=30, C=10.
//
// Round 10: R9 (MFMA 32x32, passed, 508us) was latency-bound: 1 wave/CU,
// serial chain ~1556 cyc/step, VALUBusy 15%, MfmaUtil 6%. Rebuild on
// 16x16x32 tiles with three structural fixes:
//  - ILP2: each wave runs TWO independent 16-batch chunks; 256 blocks x 1
//    wave stays 1/CU but each chunk's MFMA chain hides under the sibling's
//    VALU. 8 chains of 3 chained MFMAs (dep ~40cyc each, easily covered).
//  - Permuted A row-slices: slice0 = rows (i&3)+8*(i>>2), slice1 = +4.
//    Lane-group g's D regs are then EXACTLY true rows 8g..8g+7 = the k-range
//    its next B-frag needs: B rebuild = 12 in-lane cvt_pk, ZERO cross-lane
//    ops (R9 needed 12 permlane + layout movs).
//  - x rides the free k=30 column (A[r][30] = W_ih 3-split, B[30][b] = x
//    3-split; k=31 zero). No separate x-term, no x LDS: x prefetched from
//    global as float2/2-steps (L1-line reuse), LDS only 4KB hfin.
// Numerics: same 3-level split / 6-product set as R9 (verified pass).
// Predict: dispatch 140-170us, MfmaUtil 15-25, VALUBusy 45-60, conflicts ~0.

#define T_STEPS 784
#define NBATCH  8192
#define NH      30
#define NC      10
#define BPC     16            // batches per chunk (16x16 tile)
#define CPB     2             // chunks per wave (ILP2)
#define BPB     (BPC * CPB)   // 32 batches per block

typedef float  f32x4 __attribute__((ext_vector_type(4)));
typedef short  s16x8 __attribute__((ext_vector_type(8)));
typedef int    i32x4 __attribute__((ext_vector_type(4)));

#define MFMA16(a, b, c) __builtin_amdgcn_mfma_f32_16x16x32_bf16(a, b, c, 0, 0, 0)

__device__ __forceinline__ int cvt_pk_bf16(float lo, float hi) {
    int d;
    asm("v_cvt_pk_bf16_f32 %0, %1, %2" : "=v"(d) : "v"(lo), "v"(hi));
    return d;
}
__device__ __forceinline__ float rne_bf16(float x) {
    unsigned u = __float_as_uint(x);
    u = (u + 0x7fffu + ((u >> 16) & 1u)) & 0xffff0000u;
    return __uint_as_float(u);
}
__device__ __forceinline__ float lo16f(int p) { return __uint_as_float(((unsigned)p) << 16); }
__device__ __forceinline__ float hi16f(int p) { return __uint_as_float(((unsigned)p) & 0xffff0000u); }

__device__ __forceinline__ s16x8 pack8(const float* v) {
    i32x4 t;
    t.x = cvt_pk_bf16(v[0], v[1]);
    t.y = cvt_pk_bf16(v[2], v[3]);
    t.z = cvt_pk_bf16(v[4], v[5]);
    t.w = cvt_pk_bf16(v[6], v[7]);
    return __builtin_bit_cast(s16x8, t);
}

// 3-level bf16 split of a scalar (RNE via cvt_pk itself)
#define XSPLIT(X, XP1, XP2, XP3) \
    int XP1, XP2, XP3; { \
        XP1 = cvt_pk_bf16((X), 0.0f); \
        float r1_ = (X) - lo16f(XP1); \
        XP2 = cvt_pk_bf16(r1_, 0.0f); \
        float r2_ = r1_ - lo16f(XP2); \
        XP3 = cvt_pk_bf16(r2_, 0.0f); \
    }

// One recurrence step for one 16-batch chunk.
// FB: s16x8[3] state (h levels + x at k=30). HST: float[8] fp32 h out.
// XNEXT: x[t+1] scalar (inserted into the new FB for the next step).
// Products per slice: A1B1,A1B2,A1B3 (chain a0/b0) + A2B2,A2B1,A3B1 (a1/b1).
#define STEPC(FB, HST, XNEXT) { \
    const f32x4 z4 = {0.0f, 0.0f, 0.0f, 0.0f}; \
    f32x4 a0, a1, b0, b1; \
    a0 = MFMA16(wA[0][0], FB[0], z4); \
    b0 = MFMA16(wA[0][1], FB[0], z4); \
    a1 = MFMA16(wA[1][0], FB[1], z4); \
    b1 = MFMA16(wA[1][1], FB[1], z4); \
    a0 = MFMA16(wA[0][0], FB[1], a0); \
    b0 = MFMA16(wA[0][1], FB[1], b0); \
    a1 = MFMA16(wA[1][0], FB[0], a1); \
    b1 = MFMA16(wA[1][1], FB[0], b1); \
    a0 = MFMA16(wA[0][0], FB[2], a0); \
    b0 = MFMA16(wA[0][1], FB[2], b0); \
    a1 = MFMA16(wA[2][0], FB[0], a1); \
    b1 = MFMA16(wA[2][1], FB[0], b1); \
    _Pragma("unroll") \
    for (int j = 0; j < 4; ++j) { \
        float z = a0[j] + a1[j]; \
        HST[j] = copysignf(fmaxf(fabsf(z) + bmr[0][j], 0.0f), z); \
    } \
    _Pragma("unroll") \
    for (int j = 0; j < 4; ++j) { \
        float z = b0[j] + b1[j]; \
        HST[4 + j] = copysignf(fmaxf(fabsf(z) + bmr[1][j], 0.0f), z); \
    } \
    int P1[4], P2[4], P3[4]; \
    _Pragma("unroll") \
    for (int q = 0; q < 4; ++q) { \
        float pa = HST[2 * q], pb = HST[2 * q + 1]; \
        int p1 = cvt_pk_bf16(pa, pb); \
        float ra = pa - lo16f(p1), rb = pb - hi16f(p1); \
        int p2 = cvt_pk_bf16(ra, rb); \
        int p3 = cvt_pk_bf16(ra - lo16f(p2), rb - hi16f(p2)); \
        P1[q] = p1; P2[q] = p2; P3[q] = p3; \
    } \
    XSPLIT(XNEXT, xs1_, xs2_, xs3_) \
    i32x4 t_; \
    t_.x = P1[0]; t_.y = P1[1]; t_.z = P1[2]; t_.w = g3 ? xs1_ : P1[3]; \
    FB[0] = __builtin_bit_cast(s16x8, t_); \
    t_.x = P2[0]; t_.y = P2[1]; t_.z = P2[2]; t_.w = g3 ? xs2_ : P2[3]; \
    FB[1] = __builtin_bit_cast(s16x8, t_); \
    t_.x = P3[0]; t_.y = P3[1]; t_.z = P3[2]; t_.w = g3 ? xs3_ : P3[3]; \
    FB[2] = __builtin_bit_cast(s16x8, t_); \
}

__global__ __launch_bounds__(64, 1)
void rnn_mfma16(const float* __restrict__ inp,    // [B, T, 1]
                const float* __restrict__ W_ih,   // [H, 1]
                const float* __restrict__ W_hh,   // [H, H]
                const float* __restrict__ b_mod,  // [H]
                const float* __restrict__ W_lin,  // [C, H]
                const float* __restrict__ b_lin,  // [C]
                float* __restrict__ out)          // [B, C]
{
    __shared__ float hfin[BPB * 33];   // 4.2 KB, stride 33

    const int l   = threadIdx.x;
    const int blk = blockIdx.x;
    const int n   = l & 15;            // B/D column (batch in chunk); also A row idx
    const int g   = l >> 4;            // lane group: owns k/rows 8g..8g+7
    const bool g3 = (g == 3);

    // ---- A-frags: permuted row-slices, 3 W-levels, x column at k=30 ----
    // slice s holds true rows R = (i&3) + 8*(i>>2) + 4s for A-row i.
    // A[i][k]: i = lane&15, k = 8*(lane>>4) + e (pairs per VGPR) [32x32-analog,
    // HW-verified pattern from R9]. k==30 column = W_ih (x slot); k==31 = 0.
    s16x8 wA[3][2];
    #pragma unroll
    for (int s = 0; s < 2; ++s) {
        const int R = (n & 3) + 8 * (n >> 2) + 4 * s;
        float w1f[8], w2f[8], w3f[8];
        #pragma unroll
        for (int e = 0; e < 8; ++e) {
            const int k = 8 * g + e;
            float w = 0.0f;
            if (R < NH) {
                if (k < NH)       w = W_hh[R * NH + k];
                else if (k == NH) w = W_ih[R];         // k==30: x column
            }
            float a1 = rne_bf16(w);  float r1 = w - a1;
            float a2 = rne_bf16(r1); float r2 = r1 - a2;
            w1f[e] = a1; w2f[e] = a2; w3f[e] = r2;     // lvl3 RNE'd by pack8
        }
        wA[0][s] = pack8(w1f);
        wA[1][s] = pack8(w2f);
        wA[2][s] = pack8(w3f);
    }

    // modReLU bias per acc reg: slice s reg j <-> true row 8g + 4s + j
    float bmr[2][4];
    #pragma unroll
    for (int s = 0; s < 2; ++s)
        #pragma unroll
        for (int j = 0; j < 4; ++j) {
            const int R = 8 * g + 4 * s + j;
            bmr[s][j] = (R < NH) ? b_mod[R] : 0.0f;
        }

    // ---- x: global, register-prefetched float2 per 2 steps per chunk ----
    const float* xr0 = inp + (size_t)(blk * BPB + 0 * BPC + n) * T_STEPS;
    const float* xr1 = inp + (size_t)(blk * BPB + 1 * BPC + n) * T_STEPS;
    float2 xc0 = *(const float2*)(xr0);       // (x0, x1)
    float2 xc1 = *(const float2*)(xr1);
    float2 xn0 = *(const float2*)(xr0 + 2);   // (x2, x3)
    float2 xn1 = *(const float2*)(xr1 + 2);

    // ---- initial state: h=0, x=x[0] at k=30 (g==3, word 3 lo16) ----
    s16x8 fB0[3], fB1[3];
    {
        XSPLIT(xc0.x, i1, i2, i3)
        i32x4 t; t.x = 0; t.y = 0; t.z = 0;
        t.w = g3 ? i1 : 0; fB0[0] = __builtin_bit_cast(s16x8, t);
        t.w = g3 ? i2 : 0; fB0[1] = __builtin_bit_cast(s16x8, t);
        t.w = g3 ? i3 : 0; fB0[2] = __builtin_bit_cast(s16x8, t);
    }
    {
        XSPLIT(xc1.x, i1, i2, i3)
        i32x4 t; t.x = 0; t.y = 0; t.z = 0;
        t.w = g3 ? i1 : 0; fB1[0] = __builtin_bit_cast(s16x8, t);
        t.w = g3 ? i2 : 0; fB1[1] = __builtin_bit_cast(s16x8, t);
        t.w = g3 ? i3 : 0; fB1[2] = __builtin_bit_cast(s16x8, t);
    }

    float hst0[8], hst1[8];

    // ---- main recurrence: 392 iters x 2 steps, chunks interleaved ----
    #pragma unroll 1
    for (int m = 0; m < T_STEPS / 2; ++m) {
        int tf = 2 * m + 4; if (tf > T_STEPS - 2) tf = T_STEPS - 2;
        float2 xf0 = *(const float2*)(xr0 + tf);
        float2 xf1 = *(const float2*)(xr1 + tf);

        // step t = 2m: next x = x[2m+1] = xc.y
        STEPC(fB0, hst0, xc0.y)
        STEPC(fB1, hst1, xc1.y)
        // step t = 2m+1: next x = x[2m+2] = xn.x
        STEPC(fB0, hst0, xn0.x)
        STEPC(fB1, hst1, xn1.x)

        xc0 = xn0; xc1 = xn1;
        xn0 = xf0; xn1 = xf1;
    }

    // ---- stash final h: lane(g,n) owns true rows 8g..8g+7 of its batch ----
    #pragma unroll
    for (int j = 0; j < 8; ++j) {
        hfin[(0 * BPC + n) * 33 + 8 * g + j] = hst0[j];
        hfin[(1 * BPC + n) * 33 + 8 * g + j] = hst1[j];
    }
    __syncthreads();

    // ---- classifier: 320 outputs (32 batches x 10 classes), 5 per lane ----
    #pragma unroll
    for (int it = 0; it < 5; ++it) {
        const int kk = l + 64 * it;          // < 320
        const int bb = kk / 10;
        const int c  = kk - bb * 10;
        float acc = b_lin[c];
        #pragma unroll
        for (int i = 0; i < NH; ++i) {
            acc = fmaf(W_lin[c * NH + i], hfin[bb * 33 + i], acc);
        }
        out[((size_t)blk * BPB + bb) * NC + c] = acc;
    }
}

extern "C" void kernel_launch(void* const* d_in, const int* in_sizes, int n_in,
                              void* d_out, int out_size, void* d_ws, size_t ws_size,
                              hipStream_t stream) {
    const float* inp   = (const float*)d_in[0];
    const float* W_ih  = (const float*)d_in[1];
    const float* W_hh  = (const float*)d_in[2];
    const float* b_mod = (const float*)d_in[3];
    const float* W_lin = (const float*)d_in[4];
    const float* b_lin = (const float*)d_in[5];
    float* out = (float*)d_out;

    dim3 grid(NBATCH / BPB);   // 256 blocks, one wave each
    dim3 block(64);
    rnn_mfma16<<<grid, block, 0, stream>>>(inp, W_ih, W_hh, b_mod,
                                           W_lin, b_lin, out);
}

// Round 6
// 450.245 us; speedup vs baseline: 1.2344x; 1.1540x over previous
//
#include <hip/hip_runtime.h>

// expRNN/modReLU recurrence, B=8192, T=784, I=1, H=30, C=10.
//
// Round 11: skewed software pipeline over R10's verified MFMA16 dataflow.
// R9/R10 post-mortem: wall ~1440-1550 cyc/step with busy = 224 VALU + 95
// MFMA -> ~1120 cyc/step of UNHIDDEN MFMA<->VALU round-trip latency; the
// compiler kept the two chunks clustered in source order (ILP2 gave 8%).
// Fix: half-step skew in SOURCE order:
//   per step: MFMA(c1,t); VALU(c0,t)->FB0; MFMA(c0,t+1); VALU(c1,t)->FB1
// Every acc is consumed one full phase (~12 MFMA + ~76 VALU) after issue.
// Numerics/product set/fragment layout verbatim R10 (passed).
// x: float4 register buffers, loaded 2 iters (8 steps) ahead of use ->
// cold-HBM ~900cyc covered. Final over-issued step 784 uses clamped x,
// result discarded (finite, no NaN).
// Predict: dispatch 150-230us, MfmaUtil 12-20, VALUBusy 45-65, VGPR ~160.

#define T_STEPS 784
#define NBATCH  8192
#define NH      30
#define NC      10
#define BPC     16            // batches per chunk (16x16 tile)
#define CPB     2             // chunks per wave
#define BPB     (BPC * CPB)   // 32 batches per block

typedef float  f32x4 __attribute__((ext_vector_type(4)));
typedef short  s16x8 __attribute__((ext_vector_type(8)));
typedef int    i32x4 __attribute__((ext_vector_type(4)));

#define MFMA16(a, b, c) __builtin_amdgcn_mfma_f32_16x16x32_bf16(a, b, c, 0, 0, 0)

__device__ __forceinline__ int cvt_pk_bf16(float lo, float hi) {
    int d;
    asm("v_cvt_pk_bf16_f32 %0, %1, %2" : "=v"(d) : "v"(lo), "v"(hi));
    return d;
}
__device__ __forceinline__ float rne_bf16(float x) {
    unsigned u = __float_as_uint(x);
    u = (u + 0x7fffu + ((u >> 16) & 1u)) & 0xffff0000u;
    return __uint_as_float(u);
}
__device__ __forceinline__ float lo16f(int p) { return __uint_as_float(((unsigned)p) << 16); }
__device__ __forceinline__ float hi16f(int p) { return __uint_as_float(((unsigned)p) & 0xffff0000u); }

__device__ __forceinline__ s16x8 pack8(const float* v) {
    i32x4 t;
    t.x = cvt_pk_bf16(v[0], v[1]);
    t.y = cvt_pk_bf16(v[2], v[3]);
    t.z = cvt_pk_bf16(v[4], v[5]);
    t.w = cvt_pk_bf16(v[6], v[7]);
    return __builtin_bit_cast(s16x8, t);
}

// MFMA phase: 12 MFMAs, 4 chains of depth 3.
// chain A0: w1h1,w1h2,w1h3 (slice0)  chain A1: w2h2,w2h1,w3h1 (slice0)
// chain A2,A3: same for slice1. z(slice0)[j]=A0[j]+A1[j]; slice1: A2+A3.
#define MPHASE(A0, A1, A2, A3, FB) { \
    const f32x4 zz4 = {0.0f, 0.0f, 0.0f, 0.0f}; \
    A0 = MFMA16(wA[0][0], FB[0], zz4); \
    A1 = MFMA16(wA[1][0], FB[1], zz4); \
    A2 = MFMA16(wA[0][1], FB[0], zz4); \
    A3 = MFMA16(wA[1][1], FB[1], zz4); \
    A0 = MFMA16(wA[0][0], FB[1], A0); \
    A1 = MFMA16(wA[1][0], FB[0], A1); \
    A2 = MFMA16(wA[0][1], FB[1], A2); \
    A3 = MFMA16(wA[1][1], FB[0], A3); \
    A0 = MFMA16(wA[0][0], FB[2], A0); \
    A1 = MFMA16(wA[2][0], FB[0], A1); \
    A2 = MFMA16(wA[0][1], FB[2], A2); \
    A3 = MFMA16(wA[2][1], FB[0], A3); \
}

// VALU phase: modReLU + 3-level split + x insert (k=30 on g==3, word3.lo16).
#define VPHASE(A0, A1, A2, A3, FB, HST, XNEXT) { \
    _Pragma("unroll") \
    for (int j = 0; j < 4; ++j) { \
        float z = A0[j] + A1[j]; \
        HST[j] = copysignf(fmaxf(fabsf(z) + bmr[0][j], 0.0f), z); \
    } \
    _Pragma("unroll") \
    for (int j = 0; j < 4; ++j) { \
        float z = A2[j] + A3[j]; \
        HST[4 + j] = copysignf(fmaxf(fabsf(z) + bmr[1][j], 0.0f), z); \
    } \
    int P1[4], P2[4], P3[4]; \
    _Pragma("unroll") \
    for (int q = 0; q < 4; ++q) { \
        float pa = HST[2 * q], pb = HST[2 * q + 1]; \
        int p1 = cvt_pk_bf16(pa, pb); \
        float ra = pa - lo16f(p1), rb = pb - hi16f(p1); \
        int p2 = cvt_pk_bf16(ra, rb); \
        int p3 = cvt_pk_bf16(ra - lo16f(p2), rb - hi16f(p2)); \
        P1[q] = p1; P2[q] = p2; P3[q] = p3; \
    } \
    int xs1 = cvt_pk_bf16((XNEXT), 0.0f); \
    float xr1 = (XNEXT) - lo16f(xs1); \
    int xs2 = cvt_pk_bf16(xr1, 0.0f); \
    int xs3 = cvt_pk_bf16(xr1 - lo16f(xs2), 0.0f); \
    i32x4 t_; \
    t_.x = P1[0]; t_.y = P1[1]; t_.z = P1[2]; t_.w = g3 ? xs1 : P1[3]; \
    FB[0] = __builtin_bit_cast(s16x8, t_); \
    t_.x = P2[0]; t_.y = P2[1]; t_.z = P2[2]; t_.w = g3 ? xs2 : P2[3]; \
    FB[1] = __builtin_bit_cast(s16x8, t_); \
    t_.x = P3[0]; t_.y = P3[1]; t_.z = P3[2]; t_.w = g3 ? xs3 : P3[3]; \
    FB[2] = __builtin_bit_cast(s16x8, t_); \
}

// skewed step: on entry chunk0's accs (step t) are in flight, FB1 holds
// chunk1's step-t operands. XN0/XN1 = x[t+1] per chunk.
#define SKEWSTEP(XN0, XN1) { \
    MPHASE(c10, c11, c12, c13, fB1)               /* chunk1 step t    */ \
    VPHASE(c00, c01, c02, c03, fB0, hst0, (XN0))  /* finish c0 t      */ \
    MPHASE(c00, c01, c02, c03, fB0)               /* chunk0 step t+1  */ \
    VPHASE(c10, c11, c12, c13, fB1, hst1, (XN1))  /* finish c1 t      */ \
}

__global__ __launch_bounds__(64, 1)
void rnn_mfma_skew(const float* __restrict__ inp,    // [B, T, 1]
                   const float* __restrict__ W_ih,   // [H, 1]
                   const float* __restrict__ W_hh,   // [H, H]
                   const float* __restrict__ b_mod,  // [H]
                   const float* __restrict__ W_lin,  // [C, H]
                   const float* __restrict__ b_lin,  // [C]
                   float* __restrict__ out)          // [B, C]
{
    __shared__ float hfin[BPB * 33];   // 4.2 KB, stride 33

    const int l   = threadIdx.x;
    const int blk = blockIdx.x;
    const int n   = l & 15;            // B/D column (batch in chunk); A row idx
    const int g   = l >> 4;            // lane group: owns k/rows 8g..8g+7
    const bool g3 = (g == 3);

    // ---- x pointers + first two float4 buffers (used from t=0 / t=4) ----
    const float* xr0 = inp + (size_t)(blk * BPB + 0 * BPC + n) * T_STEPS;
    const float* xr1 = inp + (size_t)(blk * BPB + 1 * BPC + n) * T_STEPS;
    float4 xA0 = *(const float4*)(xr0);
    float4 xA1 = *(const float4*)(xr1);
    float4 xB0 = *(const float4*)(xr0 + 4);
    float4 xB1 = *(const float4*)(xr1 + 4);

    // ---- A-frags: permuted row-slices, 3 W-levels, x column at k=30 ----
    // slice s holds true rows R = (n&3) + 8*(n>>2) + 4s; k = 8g + e.
    // k==30 -> W_ih (x slot); k==31 -> 0.  (verbatim R10, HW-verified)
    s16x8 wA[3][2];
    #pragma unroll
    for (int s = 0; s < 2; ++s) {
        const int R = (n & 3) + 8 * (n >> 2) + 4 * s;
        float w1f[8], w2f[8], w3f[8];
        #pragma unroll
        for (int e = 0; e < 8; ++e) {
            const int k = 8 * g + e;
            float w = 0.0f;
            if (R < NH) {
                if (k < NH)       w = W_hh[R * NH + k];
                else if (k == NH) w = W_ih[R];         // k==30: x column
            }
            float a1 = rne_bf16(w);  float r1 = w - a1;
            float a2 = rne_bf16(r1); float r2 = r1 - a2;
            w1f[e] = a1; w2f[e] = a2; w3f[e] = r2;     // lvl3 RNE'd by pack8
        }
        wA[0][s] = pack8(w1f);
        wA[1][s] = pack8(w2f);
        wA[2][s] = pack8(w3f);
    }

    // modReLU bias per acc reg: slice s reg j <-> true row 8g + 4s + j
    float bmr[2][4];
    #pragma unroll
    for (int s = 0; s < 2; ++s)
        #pragma unroll
        for (int j = 0; j < 4; ++j) {
            const int R = 8 * g + 4 * s + j;
            bmr[s][j] = (R < NH) ? b_mod[R] : 0.0f;
        }

    // ---- initial state: h=0, x[0] at k=30 (g==3, word3 lo16) ----
    s16x8 fB0[3], fB1[3];
    {
        int i1 = cvt_pk_bf16(xA0.x, 0.0f);
        float r1 = xA0.x - lo16f(i1);
        int i2 = cvt_pk_bf16(r1, 0.0f);
        int i3 = cvt_pk_bf16(r1 - lo16f(i2), 0.0f);
        i32x4 t; t.x = 0; t.y = 0; t.z = 0;
        t.w = g3 ? i1 : 0; fB0[0] = __builtin_bit_cast(s16x8, t);
        t.w = g3 ? i2 : 0; fB0[1] = __builtin_bit_cast(s16x8, t);
        t.w = g3 ? i3 : 0; fB0[2] = __builtin_bit_cast(s16x8, t);
    }
    {
        int i1 = cvt_pk_bf16(xA1.x, 0.0f);
        float r1 = xA1.x - lo16f(i1);
        int i2 = cvt_pk_bf16(r1, 0.0f);
        int i3 = cvt_pk_bf16(r1 - lo16f(i2), 0.0f);
        i32x4 t; t.x = 0; t.y = 0; t.z = 0;
        t.w = g3 ? i1 : 0; fB1[0] = __builtin_bit_cast(s16x8, t);
        t.w = g3 ? i2 : 0; fB1[1] = __builtin_bit_cast(s16x8, t);
        t.w = g3 ? i3 : 0; fB1[2] = __builtin_bit_cast(s16x8, t);
    }

    float hst0[8], hst1[8];
    f32x4 c00, c01, c02, c03, c10, c11, c12, c13;

    // prologue: put chunk0's step 0 in flight
    MPHASE(c00, c01, c02, c03, fB0)

    // ---- main recurrence: 196 iters x 4 skewed steps ----
    #pragma unroll 1
    for (int m = 0; m < T_STEPS / 4; ++m) {
        int mf = m + 2; if (mf > 195) mf = 195;      // clamp (tail values unused)
        float4 xC0 = *(const float4*)(xr0 + 4 * mf); // for iter m+2
        float4 xC1 = *(const float4*)(xr1 + 4 * mf);

        SKEWSTEP(xA0.y, xA1.y)   // t=4m+0, next x = x[4m+1]
        SKEWSTEP(xA0.z, xA1.z)   // t=4m+1
        SKEWSTEP(xA0.w, xA1.w)   // t=4m+2
        SKEWSTEP(xB0.x, xB1.x)   // t=4m+3, next x = x[4m+4]

        xA0 = xB0; xA1 = xB1;
        xB0 = xC0; xB1 = xC1;
    }
    // loop exits with hst0/hst1 = h(783) (final); the trailing in-flight
    // MPHASE(c0, step 784) result is never consumed.

    // ---- stash final h: lane(g,n) owns true rows 8g..8g+7 of its batch ----
    #pragma unroll
    for (int j = 0; j < 8; ++j) {
        hfin[(0 * BPC + n) * 33 + 8 * g + j] = hst0[j];
        hfin[(1 * BPC + n) * 33 + 8 * g + j] = hst1[j];
    }
    __syncthreads();

    // ---- classifier: 320 outputs (32 batches x 10 classes), 5 per lane ----
    #pragma unroll
    for (int it = 0; it < 5; ++it) {
        const int kk = l + 64 * it;          // < 320
        const int bb = kk / 10;
        const int c  = kk - bb * 10;
        float acc = b_lin[c];
        #pragma unroll
        for (int i = 0; i < NH; ++i) {
            acc = fmaf(W_lin[c * NH + i], hfin[bb * 33 + i], acc);
        }
        out[((size_t)blk * BPB + bb) * NC + c] = acc;
    }
}

extern "C" void kernel_launch(void* const* d_in, const int* in_sizes, int n_in,
                              void* d_out, int out_size, void* d_ws, size_t ws_size,
                              hipStream_t stream) {
    const float* inp   = (const float*)d_in[0];
    const float* W_ih  = (const float*)d_in[1];
    const float* W_hh  = (const float*)d_in[2];
    const float* b_mod = (const float*)d_in[3];
    const float* W_lin = (const float*)d_in[4];
    const float* b_lin = (const float*)d_in[5];
    float* out = (float*)d_out;

    dim3 grid(NBATCH / BPB);   // 256 blocks, one wave each
    dim3 block(64);
    rnn_mfma_skew<<<grid, block, 0, stream>>>(inp, W_ih, W_hh, b_mod,
                                              W_lin, b_lin, out);
}